// Round 12
// baseline (239.581 us; speedup 1.0000x reference)
//
#include <hip/hip_runtime.h>

typedef unsigned short ushort_t;
typedef __attribute__((ext_vector_type(8))) short bf16x8;     // 8 bf16 in 4 VGPRs
typedef __attribute__((ext_vector_type(4))) float f32x4;
typedef __attribute__((ext_vector_type(4))) unsigned short u16x4;
typedef __attribute__((ext_vector_type(16))) float f32x16;

__device__ __forceinline__ unsigned short f2bf(float f) {
    union { float f; unsigned u; } v; v.f = f;
    unsigned r = v.u + 0x7FFFu + ((v.u >> 16) & 1u);   // RNE
    return (unsigned short)(r >> 16);
}

// v_cvt_pk_bf16_f32: lo=RNE(a), hi=RNE(b) — bit-identical to f2bf, 1 inst / 2 elems
__device__ __forceinline__ unsigned cvt_pk_bf16(float a, float b) {
    unsigned r;
    asm("v_cvt_pk_bf16_f32 %0, %1, %2" : "=v"(r) : "v"(a), "v"(b));
    return r;
}

// ================= weight prep v14: wave-per-row conv-fold via LDS =================
//  Part A (blocks 0..127):   one WAVE per fc1 row n -> zero-padded 30x30 LDS image,
//    each of the 832 outputs = 9 LDS reads + 9 FMAs (branch-free).
//  Part B (blocks 128..383): W2 transcode, 4 elems/thread, vectorized.
//  Part C (block 384):       W3 pad/transcode.
// Layout: Wf[(ngrp*KFRAGS + kfrag)*512 + (khalf*32 + r32)*8 + e] for mfma_32x32x16_bf16;
// W1eff folds the 3x3 conv into fc1 (p indexes 28x28 input, zero-padded to 832).
__global__ __launch_bounds__(256) void prep_w(const float* __restrict__ fc1_w,
                                              const float* __restrict__ cw,
                                              const float* __restrict__ fc2_w,
                                              const float* __restrict__ out_w,
                                              ushort_t* __restrict__ W1,
                                              ushort_t* __restrict__ W2,
                                              ushort_t* __restrict__ W3) {
    __shared__ float Fp[4][900];                       // 30x30 padded image per wave
    const int tid = threadIdx.x, bid = blockIdx.x;
    if (bid < 128) {
        const int wid = tid >> 6, lane = tid & 63;
        const int n = bid * 4 + wid;                   // this wave's fc1 row
        float* F = Fp[wid];
#pragma unroll
        for (int t = 0; t < 15; ++t) {                 // zero the padded frame
            const int i = t * 64 + lane;
            if (i < 900) F[i] = 0.f;
        }
        __syncthreads();
#pragma unroll
        for (int t = 0; t < 11; ++t) {                 // stage row: F[(r+2)*30 + (c+2)]
            const int i = t * 64 + lane;
            if (i < 676) {
                const int r = i / 26, c = i - r * 26;
                F[(r + 2) * 30 + (c + 2)] = fc1_w[n * 676 + i];
            }
        }
        __syncthreads();
        const float k00 = cw[0], k01 = cw[1], k02 = cw[2];
        const float k10 = cw[3], k11 = cw[4], k12 = cw[5];
        const float k20 = cw[6], k21 = cw[7], k22 = cw[8];
        const int ngrp = n >> 5, r32n = n & 31;
#pragma unroll
        for (int t = 0; t < 13; ++t) {                 // 832 outputs, 64 lanes x 13
            const int p = t * 64 + lane;
            float v = 0.f;
            if (p < 784) {
                const int pr = p / 28, pc = p - pr * 28;
                const int rb = (pr + 2) * 30 + (pc + 2);
                v = k00 * F[rb]      + k01 * F[rb - 1]  + k02 * F[rb - 2]
                  + k10 * F[rb - 30] + k11 * F[rb - 31] + k12 * F[rb - 32]
                  + k20 * F[rb - 60] + k21 * F[rb - 61] + k22 * F[rb - 62];
            }
            W1[(ngrp * 52 + (p >> 4)) * 512 + (((p >> 3) & 1) * 32 + r32n) * 8 + (p & 7)] = f2bf(v);
        }
    } else if (bid < 384) {
        const int base = (bid - 128) * 1024 + tid * 4;
        const int ngrp = base >> 14;
        const int kfrag = (base >> 9) & 31;
        const int li = base & 511;
        const int lane = li >> 3;
        const int n = ngrp * 32 + (lane & 31);
        const int p0 = kfrag * 16 + (lane >> 5) * 8 + (li & 7);
        const f32x4 v = *(const f32x4*)&fc2_w[n * 512 + p0];
        u16x4 o;
        o[0] = f2bf(v.x); o[1] = f2bf(v.y); o[2] = f2bf(v.z); o[3] = f2bf(v.w);
        *(u16x4*)&W2[base] = o;
    } else {
        for (int idx = tid; idx < 8192; idx += 256)
            W3[idx] = (idx < 5120) ? f2bf(out_w[idx]) : (ushort_t)0;
    }
}

// ================= fully-fused network, v16: wave-rotated kfrags, BK=128 =================
// 512 blocks x 64 batch rows, 512 threads (8 waves), launch_bounds(512,4): 128 regs/wave,
// 2 blocks/CU, 4 waves/SIMD. Wave w owns 64x64 (n-groups 2w,2w+1): acc[2][2] = 64 AGPR.
// THE FIX for zero pipe overlap (v4..v13 all time-sliced MFMA/LDS/L2 serially, time=sum):
//  1. per-wave kfrag ROTATION: wave w does the step's kfrags in order (ksub+w)&7 —
//     accumulation commutes, and at any instant the 4 waves/SIMD occupy DIFFERENT
//     kfrags, so one wave's W-L2 window overlaps another's MFMA burst.
//  2. BK=128 steps: 8 kfrags per barrier region (6 barriers instead of 13) — room for
//     the rotation to destagger, half the barrier drains.
//  3. Both x buffers alias hs (h written only after phase 1) -> 64KB LDS/block.
__global__ __launch_bounds__(512, 4) void mega16(const float* __restrict__ x,
                                                 const ushort_t* __restrict__ W1,
                                                 const ushort_t* __restrict__ W2,
                                                 const ushort_t* __restrict__ W3,
                                                 const float* __restrict__ b1,
                                                 const float* __restrict__ b2,
                                                 const float* __restrict__ ob,
                                                 float* __restrict__ out) {
    extern __shared__ ushort_t smem[];
    ushort_t* hs = smem;                 // [64][512] 64 KB h1/h2 tile
    ushort_t* xbA = smem;                // x buffer A [64][128] 16 KB (aliases hs bytes 0..16K)
    ushort_t* xbB = smem + 8192;         // x buffer B [64][128] 16 KB (aliases hs bytes 16K..32K)

    const int tid = threadIdx.x;
    const int wave = tid >> 6, lane = tid & 63;
    const int r32 = lane & 31, khalf = lane >> 5;
    const int xrow = tid >> 3, xoct = tid & 7;          // x staging: 64 rows x 8 octs(16 cols)
    const int m0 = blockIdx.x * 64;
    const size_t ng0 = wave * 2, ng1 = wave * 2 + 1;    // this wave's two n-groups

    // per-lane fragment base pointers (loop-invariant)
    const ushort_t* w1p0 = &W1[ng0 * 52 * 512 + lane * 8];
    const ushort_t* w1p1 = &W1[ng1 * 52 * 512 + lane * 8];
    const ushort_t* w2p0 = &W2[ng0 * 32 * 512 + lane * 8];
    const ushort_t* w2p1 = &W2[ng1 * 32 * 512 + lane * 8];

    f32x16 acc[2][2];                                   // [i = m-frag][j = ngrp]; 64 AGPR
#pragma unroll
    for (int a = 0; a < 2; ++a)
#pragma unroll
        for (int j = 0; j < 2; ++j)
#pragma unroll
            for (int e = 0; e < 16; ++e) acc[a][j][e] = 0.f;

    // ---- x prefetch: 16 cols of one row / thread (4 x f32x4), one BK=128 step ahead ----
    f32x4 xv0, xv1, xv2, xv3;
    auto load_x = [&](int ks) {
        const int gc0 = ks * 128 + xoct * 16;
        const float* p = &x[(size_t)(m0 + xrow) * 784 + gc0];
        xv0 = (gc0      < 784) ? __builtin_nontemporal_load((const f32x4*)p)       : (f32x4){0.f,0.f,0.f,0.f};
        xv1 = (gc0 + 4  < 784) ? __builtin_nontemporal_load((const f32x4*)(p + 4)) : (f32x4){0.f,0.f,0.f,0.f};
        xv2 = (gc0 + 8  < 784) ? __builtin_nontemporal_load((const f32x4*)(p + 8)) : (f32x4){0.f,0.f,0.f,0.f};
        xv3 = (gc0 + 12 < 784) ? __builtin_nontemporal_load((const f32x4*)(p + 12)): (f32x4){0.f,0.f,0.f,0.f};
    };
    auto store_x = [&](ushort_t* buf) {
        union { bf16x8 h; unsigned u[4]; } a, b;
        a.u[0] = cvt_pk_bf16(xv0.x, xv0.y); a.u[1] = cvt_pk_bf16(xv0.z, xv0.w);
        a.u[2] = cvt_pk_bf16(xv1.x, xv1.y); a.u[3] = cvt_pk_bf16(xv1.z, xv1.w);
        b.u[0] = cvt_pk_bf16(xv2.x, xv2.y); b.u[1] = cvt_pk_bf16(xv2.z, xv2.w);
        b.u[2] = cvt_pk_bf16(xv3.x, xv3.y); b.u[3] = cvt_pk_bf16(xv3.z, xv3.w);
        const int s0 = xoct * 2, sw = xrow & 7;
        *(bf16x8*)&buf[xrow * 128 + (((s0    ) ^ sw) * 8)] = a.h;
        *(bf16x8*)&buf[xrow * 128 + (((s0 + 1) ^ sw) * 8)] = b.h;
    };

    // h-epilogue: bias+relu -> hs (A-layout, seg' = seg ^ (m&7)); cols = this wave's 64 n
    auto write_h = [&](const float* __restrict__ bias) {
#pragma unroll
        for (int j = 0; j < 2; ++j) {
            const int n = (wave * 2 + j) * 32 + r32;
            const float bb = bias[n];
            const int nseg = n >> 3, nrem = n & 7;
#pragma unroll
            for (int i = 0; i < 2; ++i)
#pragma unroll
                for (int reg = 0; reg < 16; ++reg) {
                    const int m = i * 32 + 4 * khalf + (reg & 3) + 8 * (reg >> 2);
                    hs[m * 512 + ((nseg ^ (m & 7)) * 8) + nrem] = f2bf(fmaxf(acc[i][j][reg] + bb, 0.f));
                }
        }
    };

    load_x(0);
    store_x(xbA);
    __syncthreads();

    // ---------------- phase 1: K = 832 = 6 steps of BK=128 + tail kfrag 48 ----------------
    for (int ks = 0; ks < 6; ++ks) {
        load_x(ks + 1);                                 // next step's x flies under the MFMAs
        const ushort_t* bufp = (ks & 1) ? xbB : xbA;
#pragma unroll
        for (int ksub = 0; ksub < 8; ++ksub) {
            const int kq = (ksub + wave) & 7;           // wave-rotated kfrag order
            const int kf = ks * 8 + kq;
            const bf16x8 bw0 = *(const bf16x8*)(w1p0 + (size_t)kf * 512);
            const bf16x8 bw1 = *(const bf16x8*)(w1p1 + (size_t)kf * 512);
            const int q = 2 * kq + khalf;               // 16B-seg index within buf row (0..15)
            bf16x8 af[2];
#pragma unroll
            for (int i = 0; i < 2; ++i) {
                const int m = i * 32 + r32;
                af[i] = *(const bf16x8*)&bufp[m * 128 + ((q ^ (m & 7)) * 8)];
            }
            __builtin_amdgcn_s_setprio(1);
            acc[0][0] = __builtin_amdgcn_mfma_f32_32x32x16_bf16(af[0], bw0, acc[0][0], 0, 0, 0);
            acc[0][1] = __builtin_amdgcn_mfma_f32_32x32x16_bf16(af[0], bw1, acc[0][1], 0, 0, 0);
            acc[1][0] = __builtin_amdgcn_mfma_f32_32x32x16_bf16(af[1], bw0, acc[1][0], 0, 0, 0);
            acc[1][1] = __builtin_amdgcn_mfma_f32_32x32x16_bf16(af[1], bw1, acc[1][1], 0, 0, 0);
            __builtin_amdgcn_s_setprio(0);
        }
        store_x((ks & 1) ? xbA : xbB);                  // fill the other buffer
        __syncthreads();
    }
    // ---- tail: kfrag 48 (cols 768..783 real; 784..831 zero pad skipped) ----
    {
        const ushort_t* bufp = xbA;                     // staged during ks=5 (odd -> store xbA)
        const bf16x8 bw0 = *(const bf16x8*)(w1p0 + (size_t)48 * 512);
        const bf16x8 bw1 = *(const bf16x8*)(w1p1 + (size_t)48 * 512);
        const int q = khalf;                            // kq = 0 within the tail step
        bf16x8 af[2];
#pragma unroll
        for (int i = 0; i < 2; ++i) {
            const int m = i * 32 + r32;
            af[i] = *(const bf16x8*)&bufp[m * 128 + ((q ^ (m & 7)) * 8)];
        }
        __builtin_amdgcn_s_setprio(1);
        acc[0][0] = __builtin_amdgcn_mfma_f32_32x32x16_bf16(af[0], bw0, acc[0][0], 0, 0, 0);
        acc[0][1] = __builtin_amdgcn_mfma_f32_32x32x16_bf16(af[0], bw1, acc[0][1], 0, 0, 0);
        acc[1][0] = __builtin_amdgcn_mfma_f32_32x32x16_bf16(af[1], bw0, acc[1][0], 0, 0, 0);
        acc[1][1] = __builtin_amdgcn_mfma_f32_32x32x16_bf16(af[1], bw1, acc[1][1], 0, 0, 0);
        __builtin_amdgcn_s_setprio(0);
    }
    __syncthreads();                                    // all x reads done before h1 overwrites

    // ---- h1 = relu(acc + b1) -> hs ----
    write_h(b1);
#pragma unroll
    for (int a = 0; a < 2; ++a)
#pragma unroll
        for (int j = 0; j < 2; ++j)
#pragma unroll
            for (int e = 0; e < 16; ++e) acc[a][j][e] = 0.f;
    __syncthreads();

    // ---------------- phase 2: K = 512, 4 groups of 8 kfrags, wave-rotated, no barriers ----
    for (int ks2 = 0; ks2 < 4; ++ks2) {
#pragma unroll
        for (int ksub = 0; ksub < 8; ++ksub) {
            const int kq = (ksub + wave) & 7;
            const int kf = ks2 * 8 + kq;
            const bf16x8 bw0 = *(const bf16x8*)(w2p0 + (size_t)kf * 512);
            const bf16x8 bw1 = *(const bf16x8*)(w2p1 + (size_t)kf * 512);
            const int hq = kf * 2 + khalf;              // 16B-seg index within hs row (0..63)
            bf16x8 af[2];
#pragma unroll
            for (int i = 0; i < 2; ++i) {
                const int m = i * 32 + r32;
                af[i] = *(const bf16x8*)&hs[m * 512 + ((hq ^ (m & 7)) * 8)];
            }
            __builtin_amdgcn_s_setprio(1);
            acc[0][0] = __builtin_amdgcn_mfma_f32_32x32x16_bf16(af[0], bw0, acc[0][0], 0, 0, 0);
            acc[0][1] = __builtin_amdgcn_mfma_f32_32x32x16_bf16(af[0], bw1, acc[0][1], 0, 0, 0);
            acc[1][0] = __builtin_amdgcn_mfma_f32_32x32x16_bf16(af[1], bw0, acc[1][0], 0, 0, 0);
            acc[1][1] = __builtin_amdgcn_mfma_f32_32x32x16_bf16(af[1], bw1, acc[1][1], 0, 0, 0);
            __builtin_amdgcn_s_setprio(0);
        }
    }
    __syncthreads();                                    // all hs(h1) reads done

    // ---- h2 = relu(acc + b2) -> hs ----
    write_h(b2);
    __syncthreads();

    // ---------------- head: waves 0..3 -> 16 rows each, K=512, direct stores ----------------
    if (wave < 4) {
        const int quad = lane >> 4, l16 = lane & 15;
        const int row = wave * 16 + l16;
        f32x4 hacc = {0.f, 0.f, 0.f, 0.f};
#pragma unroll
        for (int ks = 0; ks < 16; ++ks) {
            const int seg = 4 * ks + quad;
            const bf16x8 a = *(const bf16x8*)&hs[row * 512 + ((seg ^ (row & 7)) * 8)];
            const bf16x8 b = *(const bf16x8*)&W3[l16 * 512 + ks * 32 + quad * 8];
            hacc = __builtin_amdgcn_mfma_f32_16x16x32_bf16(a, b, hacc, 0, 0, 0);
        }
        if (l16 < 10) {
            const float bb = ob[l16];
#pragma unroll
            for (int r = 0; r < 4; ++r)
                out[(size_t)(m0 + wave * 16 + quad * 4 + r) * 10 + l16] = hacc[r] + bb;
        }
    }
}

extern "C" void kernel_launch(void* const* d_in, const int* in_sizes, int n_in,
                              void* d_out, int out_size, void* d_ws, size_t ws_size,
                              hipStream_t stream) {
    const float* x      = (const float*)d_in[0];
    const float* conv_w = (const float*)d_in[1];
    const float* fc1_w  = (const float*)d_in[2];
    const float* fc1_b  = (const float*)d_in[3];
    const float* fc2_w  = (const float*)d_in[4];
    const float* fc2_b  = (const float*)d_in[5];
    const float* out_w  = (const float*)d_in[6];
    const float* out_b  = (const float*)d_in[7];
    float* out = (float*)d_out;

    // workspace: W1f | W2f | W3 (≈1.4 MB total), fragment-major layouts
    ushort_t* W1 = (ushort_t*)d_ws;                    // 16*52*512
    ushort_t* W2 = W1 + 425984;                        // 16*32*512
    ushort_t* W3 = W2 + 262144;                        // 16*512

    prep_w<<<dim3(385), 256, 0, stream>>>(fc1_w, conv_w, fc2_w, out_w, W1, W2, W3);

    // 512 blocks x 64 rows; 512 threads (8 waves); 64 KB dynamic LDS (x buffers alias hs)
    // -> 2 blocks/CU, 4 waves/SIMD; wave-rotated kfrags + BK=128 destagger the pipes
    mega16<<<dim3(512), 512, 65536, stream>>>(x, W1, W2, W3, fc1_b, fc2_b, out_b, out);
}